// Round 1
// baseline (1075.048 us; speedup 1.0000x reference)
//
#include <hip/hip_runtime.h>
#include <hip/hip_bf16.h>
#include <math.h>

// Problem dims
#define BB 8
#define SS 32
#define NN 512
#define FIN 24
#define CC 56
#define EBN 262144
#define ESN 8192
#define EDD 4
#define NG (SS*NN)   // 16384 nodes per sample in bend graph

// ---------------- prep: fold edge-logit vectors + mix softmax ----------------
// P layout: [0..3]=u_bend, [4]=c_bend, [5..8]=u_sec, [9]=c_sec, [10]=w0, [11]=w1
__global__ void prep_kernel(const float* enc_W, const float* enc_b,
                            const float* We_b, const float* a_e_b,
                            const float* We_s, const float* a_e_s,
                            const float* mix_w, float* P) {
    if (threadIdx.x == 0 && blockIdx.x == 0) {
        float tb[EDD], ts[EDD];
        for (int j = 0; j < EDD; ++j) {
            float vb = 0.f, vs = 0.f;
            for (int c = 0; c < CC; ++c) {
                vb += We_b[j*CC + c] * a_e_b[c];
                vs += We_s[j*CC + c] * a_e_s[c];
            }
            tb[j] = vb; ts[j] = vs;
        }
        float cb = 0.f, cs = 0.f;
        for (int j = 0; j < EDD; ++j) { cb += enc_b[j]*tb[j]; cs += enc_b[j]*ts[j]; }
        for (int d = 0; d < EDD; ++d) {
            float ub = 0.f, us = 0.f;
            for (int j = 0; j < EDD; ++j) {
                ub += enc_W[d*EDD + j] * tb[j];
                us += enc_W[d*EDD + j] * ts[j];
            }
            P[d] = ub; P[5 + d] = us;
        }
        P[4] = cb; P[9] = cs;
        float m0 = mix_w[0], m1 = mix_w[1];
        float mm = fmaxf(m0, m1);
        float e0 = expf(m0 - mm), e1 = expf(m1 - mm);
        float inv = 1.f / (e0 + e1);
        P[10] = e0 * inv; P[11] = e1 * inv;
    }
}

// ---------------- CSR build ----------------
__global__ void zero_counts(int* bend_cnt, int* sec_cnt) {
    int i = blockIdx.x * blockDim.x + threadIdx.x;
    if (i < NG) bend_cnt[i] = 0;
    if (i < NN) sec_cnt[i] = 0;
}

__global__ void count_kernel(const int* bend_ei, const int* sec_ei,
                             int* bend_cnt, int* sec_cnt) {
    int i = blockIdx.x * blockDim.x + threadIdx.x;
    if (i < EBN) atomicAdd(&bend_cnt[bend_ei[EBN + i]], 1);
    if (i < ESN) atomicAdd(&sec_cnt[sec_ei[ESN + i]], 1);
}

// single-block scan; block 0 = bend (16384), block 1 = section (512)
__global__ __launch_bounds__(1024) void scan_kernel(int* bend_cnt, int* bend_off, int* bend_cur,
                                                    int* sec_cnt, int* sec_off, int* sec_cur) {
    __shared__ int part[1024];
    int *cnt, *offs, *cur; int n;
    if (blockIdx.x == 0) { cnt = bend_cnt; offs = bend_off; cur = bend_cur; n = NG; }
    else                 { cnt = sec_cnt;  offs = sec_off;  cur = sec_cur;  n = NN; }
    int t = threadIdx.x;
    int ipt = (n + 1023) / 1024;
    int base = t * ipt;
    int local = 0;
    for (int k = 0; k < ipt; ++k) { int i = base + k; if (i < n) local += cnt[i]; }
    part[t] = local;
    __syncthreads();
    for (int d = 1; d < 1024; d <<= 1) {
        int v = (t >= d) ? part[t - d] : 0;
        __syncthreads();
        part[t] += v;
        __syncthreads();
    }
    int run = (t == 0) ? 0 : part[t - 1];
    for (int k = 0; k < ipt; ++k) {
        int i = base + k;
        if (i < n) { offs[i] = run; cur[i] = run; run += cnt[i]; }
    }
    if (t == 1023) offs[n] = part[1023];
}

__global__ void fill_kernel(const int* bend_ei, const int* sec_ei,
                            int* bend_cur, int* bend_eids,
                            int* sec_cur, int* sec_eids) {
    int i = blockIdx.x * blockDim.x + threadIdx.x;
    if (i < EBN) { int d = bend_ei[EBN + i]; int p = atomicAdd(&bend_cur[d], 1); bend_eids[p] = i; }
    if (i < ESN) { int d = sec_ei[ESN + i]; int p = atomicAdd(&sec_cur[d], 1); sec_eids[p] = i; }
}

// ---------------- node features: h = x@W, alpha_src/dst = h . a ----------------
// one wave per (b, g); lane = channel
__global__ void feat_kernel(const float* x,
                            const float* Wb, const float* a_src_b, const float* a_dst_b,
                            const float* Ws, const float* a_src_s, const float* a_dst_s,
                            float* h_b, float* h_s,
                            float* asb, float* adb, float* ass, float* ads) {
    int wave = (blockIdx.x * blockDim.x + threadIdx.x) >> 6;
    int lane = threadIdx.x & 63;
    if (wave >= BB * NG) return;
    size_t ng = (size_t)wave;           // = b*NG + g
    const float* xr = x + ng * FIN;
    float xv[FIN];
    const float4* x4 = (const float4*)xr;
    #pragma unroll
    for (int q = 0; q < FIN/4; ++q) {
        float4 v = x4[q];
        xv[q*4+0] = v.x; xv[q*4+1] = v.y; xv[q*4+2] = v.z; xv[q*4+3] = v.w;
    }
    float hb = 0.f, hs = 0.f;
    if (lane < CC) {
        #pragma unroll
        for (int f = 0; f < FIN; ++f) {
            hb = fmaf(xv[f], Wb[f*CC + lane], hb);
            hs = fmaf(xv[f], Ws[f*CC + lane], hs);
        }
    }
    float vsb = (lane < CC) ? hb * a_src_b[lane] : 0.f;
    float vdb = (lane < CC) ? hb * a_dst_b[lane] : 0.f;
    float vss = (lane < CC) ? hs * a_src_s[lane] : 0.f;
    float vds = (lane < CC) ? hs * a_dst_s[lane] : 0.f;
    #pragma unroll
    for (int o = 32; o > 0; o >>= 1) {
        vsb += __shfl_down(vsb, o);
        vdb += __shfl_down(vdb, o);
        vss += __shfl_down(vss, o);
        vds += __shfl_down(vds, o);
    }
    if (lane == 0) { asb[ng] = vsb; adb[ng] = vdb; ass[ng] = vss; ads[ng] = vds; }
    if (lane < CC) { h_b[ng*CC + lane] = hb; h_s[ng*CC + lane] = hs; }
}

// ---------------- per-edge scalar logit term ----------------
__global__ void elog_kernel(const float* bend_attr, const float* sec_attr,
                            const float* P, float* elog_b, float* elog_s) {
    int i = blockIdx.x * blockDim.x + threadIdx.x;
    const int nb = BB * EBN;
    const int ntot = nb + BB * ESN;
    if (i >= ntot) return;
    if (i < nb) {
        float4 a = ((const float4*)bend_attr)[i];
        elog_b[i] = a.x*P[0] + a.y*P[1] + a.z*P[2] + a.w*P[3] + P[4];
    } else {
        int j = i - nb;
        float4 a = ((const float4*)sec_attr)[j];
        elog_s[j] = a.x*P[5] + a.y*P[6] + a.z*P[7] + a.w*P[8] + P[9];
    }
}

// ---------------- bend gather: out = w0 * leaky(GAT_bend, 0.01) ----------------
__global__ void bend_gather(const int* bend_ei, const int* bend_off, const int* bend_eids,
                            const float* h_b, const float* asb, const float* adb,
                            const float* elog_b, const float* bias_b, const float* P,
                            float* out) {
    int wave = (blockIdx.x * blockDim.x + threadIdx.x) >> 6;
    int lane = threadIdx.x & 63;
    if (wave >= BB * NG) return;
    int b = wave / NG, g = wave - b * NG;
    int beg = bend_off[g], end = bend_off[g + 1];
    const float* as_b = asb + (size_t)b * NG;
    const float* el   = elog_b + (size_t)b * EBN;
    const float* hbb  = h_b + (size_t)b * NG * CC;
    float adg = adb[(size_t)b * NG + g];
    float m = -INFINITY;
    for (int k = beg; k < end; ++k) {
        int e = bend_eids[k];
        int s = bend_ei[e];
        float lg = as_b[s] + adg + el[e];
        lg = lg >= 0.f ? lg : 0.2f * lg;
        m = fmaxf(m, lg);
    }
    float sum = 0.f, acc = 0.f;
    for (int k = beg; k < end; ++k) {
        int e = bend_eids[k];
        int s = bend_ei[e];
        float lg = as_b[s] + adg + el[e];
        lg = lg >= 0.f ? lg : 0.2f * lg;
        float p = __expf(lg - m);
        sum += p;
        if (lane < CC) acc = fmaf(p, hbb[(size_t)s * CC + lane], acc);
    }
    if (lane < CC) {
        float v = acc / (sum + 1e-16f) + bias_b[lane];
        v = v >= 0.f ? v : 0.01f * v;
        out[((size_t)b * NG + g) * CC + lane] = P[10] * v;
    }
}

// ---------------- section gather: out += w1 * GAT_sec ----------------
__global__ void sec_gather(const int* sec_ei, const int* sec_off, const int* sec_eids,
                           const float* h_s, const float* ass, const float* ads,
                           const float* elog_s, const float* bias_s, const float* P,
                           float* out) {
    int wave = (blockIdx.x * blockDim.x + threadIdx.x) >> 6;
    int lane = threadIdx.x & 63;
    if (wave >= BB * NG) return;
    int b = wave / NG, g = wave - b * NG;
    int sct = g / NN, n = g - sct * NN;
    int beg = sec_off[n], end = sec_off[n + 1];
    const float* el = elog_s + (size_t)b * ESN;
    size_t basebg = (size_t)b * NG + (size_t)sct * NN;   // node base for this (b, section)
    float adg = ads[basebg + n];
    float m = -INFINITY;
    for (int k = beg; k < end; ++k) {
        int e = sec_eids[k];
        int s = sec_ei[e];
        float lg = ass[basebg + s] + adg + el[e];
        lg = lg >= 0.f ? lg : 0.2f * lg;
        m = fmaxf(m, lg);
    }
    float sum = 0.f, acc = 0.f;
    for (int k = beg; k < end; ++k) {
        int e = sec_eids[k];
        int s = sec_ei[e];
        float lg = ass[basebg + s] + adg + el[e];
        lg = lg >= 0.f ? lg : 0.2f * lg;
        float p = __expf(lg - m);
        sum += p;
        if (lane < CC) acc = fmaf(p, h_s[(basebg + s) * CC + lane], acc);
    }
    if (lane < CC) {
        float v = acc / (sum + 1e-16f) + bias_s[lane];
        out[((size_t)b * NG + g) * CC + lane] += P[11] * v;
    }
}

extern "C" void kernel_launch(void* const* d_in, const int* in_sizes, int n_in,
                              void* d_out, int out_size, void* d_ws, size_t ws_size,
                              hipStream_t stream) {
    const float* x          = (const float*)d_in[0];
    const int*   bend_ei    = (const int*)d_in[1];
    const int*   sec_ei     = (const int*)d_in[2];
    const float* bend_attr  = (const float*)d_in[3];
    const float* sec_attr   = (const float*)d_in[4];
    const float* enc_W      = (const float*)d_in[5];
    const float* enc_b      = (const float*)d_in[6];
    const float* Wb         = (const float*)d_in[7];
    const float* a_src_b    = (const float*)d_in[8];
    const float* a_dst_b    = (const float*)d_in[9];
    // d_in[10] = We_b, d_in[11] = a_e_b (only used in prep)
    const float* We_b       = (const float*)d_in[10];
    const float* a_e_b      = (const float*)d_in[11];
    const float* bias_b     = (const float*)d_in[12];
    const float* Ws         = (const float*)d_in[13];
    const float* a_src_s    = (const float*)d_in[14];
    const float* a_dst_s    = (const float*)d_in[15];
    const float* We_s       = (const float*)d_in[16];
    const float* a_e_s      = (const float*)d_in[17];
    const float* bias_s     = (const float*)d_in[18];
    const float* mix_w      = (const float*)d_in[19];
    float* out = (float*)d_out;

    // workspace layout (256B aligned chunks)
    char* base = (char*)d_ws;
    size_t off = 0;
    auto alloc = [&](size_t bytes) -> char* {
        off = (off + 255) & ~(size_t)255;
        char* p = base + off;
        off += bytes;
        return p;
    };
    float* P        = (float*)alloc(64 * sizeof(float));
    int* bend_off_a = (int*)alloc((NG + 1) * sizeof(int));
    int* bend_cur   = (int*)alloc(NG * sizeof(int));
    int* bend_eids  = (int*)alloc(EBN * sizeof(int));
    int* sec_off_a  = (int*)alloc((NN + 1) * sizeof(int));
    int* sec_cur    = (int*)alloc(NN * sizeof(int));
    int* sec_eids   = (int*)alloc(ESN * sizeof(int));
    int* bend_cnt   = (int*)alloc(NG * sizeof(int));
    int* sec_cnt    = (int*)alloc(NN * sizeof(int));
    float* h_b      = (float*)alloc((size_t)BB * NG * CC * sizeof(float));
    float* h_s      = (float*)alloc((size_t)BB * NG * CC * sizeof(float));
    float* asb      = (float*)alloc((size_t)BB * NG * sizeof(float));
    float* adb      = (float*)alloc((size_t)BB * NG * sizeof(float));
    float* ass      = (float*)alloc((size_t)BB * NG * sizeof(float));
    float* ads      = (float*)alloc((size_t)BB * NG * sizeof(float));
    float* elog_b   = (float*)alloc((size_t)BB * EBN * sizeof(float));
    float* elog_s   = (float*)alloc((size_t)BB * ESN * sizeof(float));
    (void)ws_size; (void)in_sizes; (void)n_in; (void)out_size;

    prep_kernel<<<1, 64, 0, stream>>>(enc_W, enc_b, We_b, a_e_b, We_s, a_e_s, mix_w, P);
    zero_counts<<<(NG + 255) / 256, 256, 0, stream>>>(bend_cnt, sec_cnt);
    count_kernel<<<(EBN + 255) / 256, 256, 0, stream>>>(bend_ei, sec_ei, bend_cnt, sec_cnt);
    scan_kernel<<<2, 1024, 0, stream>>>(bend_cnt, bend_off_a, bend_cur, sec_cnt, sec_off_a, sec_cur);
    fill_kernel<<<(EBN + 255) / 256, 256, 0, stream>>>(bend_ei, sec_ei, bend_cur, bend_eids, sec_cur, sec_eids);

    {
        int waves = BB * NG;
        int blocks = (waves * 64 + 255) / 256;
        feat_kernel<<<blocks, 256, 0, stream>>>(x, Wb, a_src_b, a_dst_b, Ws, a_src_s, a_dst_s,
                                                h_b, h_s, asb, adb, ass, ads);
    }
    {
        int ntot = BB * EBN + BB * ESN;
        elog_kernel<<<(ntot + 255) / 256, 256, 0, stream>>>(bend_attr, sec_attr, P, elog_b, elog_s);
    }
    {
        int waves = BB * NG;
        int blocks = (waves * 64 + 255) / 256;
        bend_gather<<<blocks, 256, 0, stream>>>(bend_ei, bend_off_a, bend_eids, h_b, asb, adb,
                                                elog_b, bias_b, P, out);
        sec_gather<<<blocks, 256, 0, stream>>>(sec_ei, sec_off_a, sec_eids, h_s, ass, ads,
                                               elog_s, bias_s, P, out);
    }
}

// Round 2
// 325.418 us; speedup vs baseline: 3.3036x; 3.3036x over previous
//
#include <hip/hip_runtime.h>
#include <hip/hip_bf16.h>
#include <math.h>

// Problem dims
#define BB 8
#define SS 32
#define NN 512
#define FIN 24
#define CC 56
#define EBN 262144
#define ESN 8192
#define EDD 4
#define NG (SS*NN)   // 16384 nodes per sample in bend graph

// ---------------- prep: fold edge-logit vectors + mix softmax ----------------
// P layout: [0..3]=u_bend, [4]=c_bend, [5..8]=u_sec, [9]=c_sec, [10]=w0, [11]=w1
__global__ void prep_kernel(const float* enc_W, const float* enc_b,
                            const float* We_b, const float* a_e_b,
                            const float* We_s, const float* a_e_s,
                            const float* mix_w, float* P) {
    if (threadIdx.x == 0 && blockIdx.x == 0) {
        float tb[EDD], ts[EDD];
        for (int j = 0; j < EDD; ++j) {
            float vb = 0.f, vs = 0.f;
            for (int c = 0; c < CC; ++c) {
                vb += We_b[j*CC + c] * a_e_b[c];
                vs += We_s[j*CC + c] * a_e_s[c];
            }
            tb[j] = vb; ts[j] = vs;
        }
        float cb = 0.f, cs = 0.f;
        for (int j = 0; j < EDD; ++j) { cb += enc_b[j]*tb[j]; cs += enc_b[j]*ts[j]; }
        for (int d = 0; d < EDD; ++d) {
            float ub = 0.f, us = 0.f;
            for (int j = 0; j < EDD; ++j) {
                ub += enc_W[d*EDD + j] * tb[j];
                us += enc_W[d*EDD + j] * ts[j];
            }
            P[d] = ub; P[5 + d] = us;
        }
        P[4] = cb; P[9] = cs;
        float m0 = mix_w[0], m1 = mix_w[1];
        float mm = fmaxf(m0, m1);
        float e0 = expf(m0 - mm), e1 = expf(m1 - mm);
        float inv = 1.f / (e0 + e1);
        P[10] = e0 * inv; P[11] = e1 * inv;
    }
}

// ---------------- CSR build ----------------
__global__ void zero_counts(int* bend_cnt, int* sec_cnt) {
    int i = blockIdx.x * blockDim.x + threadIdx.x;
    if (i < NG) bend_cnt[i] = 0;
    if (i < NN) sec_cnt[i] = 0;
}

__global__ void count_kernel(const int* bend_ei, const int* sec_ei,
                             int* bend_cnt, int* sec_cnt) {
    int i = blockIdx.x * blockDim.x + threadIdx.x;
    if (i < EBN) atomicAdd(&bend_cnt[bend_ei[EBN + i]], 1);
    if (i < ESN) atomicAdd(&sec_cnt[sec_ei[ESN + i]], 1);
}

// single-block scan; block 0 = bend (16384), block 1 = section (512)
__global__ __launch_bounds__(1024) void scan_kernel(int* bend_cnt, int* bend_off, int* bend_cur,
                                                    int* sec_cnt, int* sec_off, int* sec_cur) {
    __shared__ int part[1024];
    int *cnt, *offs, *cur; int n;
    if (blockIdx.x == 0) { cnt = bend_cnt; offs = bend_off; cur = bend_cur; n = NG; }
    else                 { cnt = sec_cnt;  offs = sec_off;  cur = sec_cur;  n = NN; }
    int t = threadIdx.x;
    int ipt = (n + 1023) / 1024;
    int base = t * ipt;
    int local = 0;
    for (int k = 0; k < ipt; ++k) { int i = base + k; if (i < n) local += cnt[i]; }
    part[t] = local;
    __syncthreads();
    for (int d = 1; d < 1024; d <<= 1) {
        int v = (t >= d) ? part[t - d] : 0;
        __syncthreads();
        part[t] += v;
        __syncthreads();
    }
    int run = (t == 0) ? 0 : part[t - 1];
    for (int k = 0; k < ipt; ++k) {
        int i = base + k;
        if (i < n) { offs[i] = run; cur[i] = run; run += cnt[i]; }
    }
    if (t == 1023) offs[n] = part[1023];
}

// fill CSR: edge ids AND source node ids in CSR order (kills the indirection
// chain in the gather kernel)
__global__ void fill_kernel(const int* bend_ei, const int* sec_ei,
                            int* bend_cur, int* bend_eids, int* bend_srcs,
                            int* sec_cur, int* sec_eids, int* sec_srcs) {
    int i = blockIdx.x * blockDim.x + threadIdx.x;
    if (i < EBN) {
        int d = bend_ei[EBN + i];
        int p = atomicAdd(&bend_cur[d], 1);
        bend_eids[p] = i;
        bend_srcs[p] = bend_ei[i];
    }
    if (i < ESN) {
        int d = sec_ei[ESN + i];
        int p = atomicAdd(&sec_cur[d], 1);
        sec_eids[p] = i;
        sec_srcs[p] = sec_ei[i];
    }
}

// ---------------- node features: h = x@W, alpha_src/dst = h . a ----------------
__global__ void feat_kernel(const float* x,
                            const float* Wb, const float* a_src_b, const float* a_dst_b,
                            const float* Ws, const float* a_src_s, const float* a_dst_s,
                            float* h_b, float* h_s,
                            float* asb, float* adb, float* ass, float* ads) {
    int wave = (blockIdx.x * blockDim.x + threadIdx.x) >> 6;
    int lane = threadIdx.x & 63;
    if (wave >= BB * NG) return;
    size_t ng = (size_t)wave;
    const float* xr = x + ng * FIN;
    float xv[FIN];
    const float4* x4 = (const float4*)xr;
    #pragma unroll
    for (int q = 0; q < FIN/4; ++q) {
        float4 v = x4[q];
        xv[q*4+0] = v.x; xv[q*4+1] = v.y; xv[q*4+2] = v.z; xv[q*4+3] = v.w;
    }
    float hb = 0.f, hs = 0.f;
    if (lane < CC) {
        #pragma unroll
        for (int f = 0; f < FIN; ++f) {
            hb = fmaf(xv[f], Wb[f*CC + lane], hb);
            hs = fmaf(xv[f], Ws[f*CC + lane], hs);
        }
    }
    float vsb = (lane < CC) ? hb * a_src_b[lane] : 0.f;
    float vdb = (lane < CC) ? hb * a_dst_b[lane] : 0.f;
    float vss = (lane < CC) ? hs * a_src_s[lane] : 0.f;
    float vds = (lane < CC) ? hs * a_dst_s[lane] : 0.f;
    #pragma unroll
    for (int o = 32; o > 0; o >>= 1) {
        vsb += __shfl_down(vsb, o);
        vdb += __shfl_down(vdb, o);
        vss += __shfl_down(vss, o);
        vds += __shfl_down(vds, o);
    }
    if (lane == 0) { asb[ng] = vsb; adb[ng] = vdb; ass[ng] = vss; ads[ng] = vds; }
    if (lane < CC) { h_b[ng*CC + lane] = hb; h_s[ng*CC + lane] = hs; }
}

// ---------------- per-edge scalar logit term (coalesced pass) ----------------
__global__ void elog_kernel(const float* bend_attr, const float* sec_attr,
                            const float* P, float* elog_b, float* elog_s) {
    int i = blockIdx.x * blockDim.x + threadIdx.x;
    const int nb = BB * EBN;
    const int ntot = nb + BB * ESN;
    if (i >= ntot) return;
    if (i < nb) {
        float4 a = ((const float4*)bend_attr)[i];
        elog_b[i] = a.x*P[0] + a.y*P[1] + a.z*P[2] + a.w*P[3] + P[4];
    } else {
        int j = i - nb;
        float4 a = ((const float4*)sec_attr)[j];
        elog_s[j] = a.x*P[5] + a.y*P[6] + a.z*P[7] + a.w*P[8] + P[9];
    }
}

// ---------------- wave reduce helpers ----------------
__device__ __forceinline__ float wave_max(float v) {
    #pragma unroll
    for (int o = 32; o > 0; o >>= 1) v = fmaxf(v, __shfl_xor(v, o));
    return v;
}
__device__ __forceinline__ float wave_sum(float v) {
    #pragma unroll
    for (int o = 32; o > 0; o >>= 1) v += __shfl_xor(v, o);
    return v;
}

// one GAT destination node, lane-parallel over edges.
// srcs/eids: CSR arrays; asrc: per-batch alpha_src base; el: per-batch edge logit
// base; h: per-(batch[,section]) feature base; adg: alpha_dst of this node.
__device__ __forceinline__ float gat_node(const int* __restrict__ srcs,
                                          const int* __restrict__ eids,
                                          const float* __restrict__ asrc,
                                          const float* __restrict__ el,
                                          const float* __restrict__ h,
                                          float adg, int beg, int end, int lane) {
    int deg = end - beg;
    if (deg <= 0) return 0.f;
    int cl = lane < CC ? lane : CC - 1;
    float acc = 0.f, sum;
    if (deg <= 64) {
        bool v = lane < deg;
        int k = beg + (v ? lane : 0);
        int s = srcs[k];
        int e = eids[k];
        float lg = asrc[s] + adg + el[e];
        lg = lg >= 0.f ? lg : 0.2f * lg;
        if (!v) lg = -INFINITY;
        float m = wave_max(lg);
        float p = v ? __expf(lg - m) : 0.f;
        sum = wave_sum(p);
        int k2 = 0;
        for (; k2 + 4 <= deg; k2 += 4) {
            float p0 = __shfl(p, k2),   p1 = __shfl(p, k2+1);
            float p2 = __shfl(p, k2+2), p3 = __shfl(p, k2+3);
            int s0 = __shfl(s, k2),   s1 = __shfl(s, k2+1);
            int s2 = __shfl(s, k2+2), s3 = __shfl(s, k2+3);
            float h0 = h[s0*CC + cl];
            float h1 = h[s1*CC + cl];
            float h2 = h[s2*CC + cl];
            float h3 = h[s3*CC + cl];
            acc = fmaf(p0, h0, acc);
            acc = fmaf(p1, h1, acc);
            acc = fmaf(p2, h2, acc);
            acc = fmaf(p3, h3, acc);
        }
        for (; k2 < deg; ++k2) {
            float pk = __shfl(p, k2);
            int sk = __shfl(s, k2);
            acc = fmaf(pk, h[sk*CC + cl], acc);
        }
    } else {
        // rare fallback: degree > 64, chunked two-pass
        float m = -INFINITY;
        for (int k0 = beg; k0 < end; k0 += 64) {
            int k = k0 + lane;
            if (k < end) {
                float lg = asrc[srcs[k]] + adg + el[eids[k]];
                lg = lg >= 0.f ? lg : 0.2f * lg;
                m = fmaxf(m, lg);
            }
        }
        m = wave_max(m);
        sum = 0.f;
        for (int k0 = beg; k0 < end; k0 += 64) {
            int k = k0 + lane;
            bool v = k < end;
            int kk = v ? k : beg;
            int s = srcs[kk];
            float lg = asrc[s] + adg + el[eids[kk]];
            lg = lg >= 0.f ? lg : 0.2f * lg;
            float p = v ? __expf(lg - m) : 0.f;
            sum += wave_sum(p);
            int valid = (end - k0) < 64 ? (end - k0) : 64;
            for (int k2 = 0; k2 < valid; ++k2) {
                float pk = __shfl(p, k2);
                int sk = __shfl(s, k2);
                acc = fmaf(pk, h[sk*CC + cl], acc);
            }
        }
    }
    return acc / (sum + 1e-16f);
}

// ---------------- fused gather: out = w0*leaky(bendGAT+bias_b) + w1*(secGAT+bias_s)
__global__ __launch_bounds__(256) void gather_fused(
        const int* __restrict__ bend_off, const int* __restrict__ bend_srcs,
        const int* __restrict__ bend_eids,
        const int* __restrict__ sec_off, const int* __restrict__ sec_srcs,
        const int* __restrict__ sec_eids,
        const float* __restrict__ h_b, const float* __restrict__ h_s,
        const float* __restrict__ asb, const float* __restrict__ adb,
        const float* __restrict__ ass, const float* __restrict__ ads,
        const float* __restrict__ elog_b, const float* __restrict__ elog_s,
        const float* __restrict__ bias_b, const float* __restrict__ bias_s,
        const float* __restrict__ P, float* __restrict__ out) {
    int wave = (blockIdx.x * blockDim.x + threadIdx.x) >> 6;
    int lane = threadIdx.x & 63;
    if (wave >= BB * NG) return;
    int b = wave >> 14;          // NG = 2^14
    int g = wave & (NG - 1);

    float vb = gat_node(bend_srcs, bend_eids,
                        asb + (size_t)b * NG, elog_b + (size_t)b * EBN,
                        h_b + (size_t)b * NG * CC,
                        adb[(size_t)b * NG + g],
                        bend_off[g], bend_off[g + 1], lane);

    int sct = g >> 9;            // NN = 2^9
    int n = g & (NN - 1);
    size_t basebg = (size_t)b * NG + (size_t)sct * NN;
    float vs = gat_node(sec_srcs, sec_eids,
                        ass + basebg, elog_s + (size_t)b * ESN,
                        h_s + basebg * CC,
                        ads[basebg + n],
                        sec_off[n], sec_off[n + 1], lane);

    if (lane < CC) {
        float ob = vb + bias_b[lane];
        ob = ob >= 0.f ? ob : 0.01f * ob;
        float os = vs + bias_s[lane];
        out[(size_t)wave * CC + lane] = P[10] * ob + P[11] * os;
    }
}

extern "C" void kernel_launch(void* const* d_in, const int* in_sizes, int n_in,
                              void* d_out, int out_size, void* d_ws, size_t ws_size,
                              hipStream_t stream) {
    const float* x          = (const float*)d_in[0];
    const int*   bend_ei    = (const int*)d_in[1];
    const int*   sec_ei     = (const int*)d_in[2];
    const float* bend_attr  = (const float*)d_in[3];
    const float* sec_attr   = (const float*)d_in[4];
    const float* enc_W      = (const float*)d_in[5];
    const float* enc_b      = (const float*)d_in[6];
    const float* Wb         = (const float*)d_in[7];
    const float* a_src_b    = (const float*)d_in[8];
    const float* a_dst_b    = (const float*)d_in[9];
    const float* We_b       = (const float*)d_in[10];
    const float* a_e_b      = (const float*)d_in[11];
    const float* bias_b     = (const float*)d_in[12];
    const float* Ws         = (const float*)d_in[13];
    const float* a_src_s    = (const float*)d_in[14];
    const float* a_dst_s    = (const float*)d_in[15];
    const float* We_s       = (const float*)d_in[16];
    const float* a_e_s      = (const float*)d_in[17];
    const float* bias_s     = (const float*)d_in[18];
    const float* mix_w      = (const float*)d_in[19];
    float* out = (float*)d_out;

    char* base = (char*)d_ws;
    size_t off = 0;
    auto alloc = [&](size_t bytes) -> char* {
        off = (off + 255) & ~(size_t)255;
        char* p = base + off;
        off += bytes;
        return p;
    };
    float* P        = (float*)alloc(64 * sizeof(float));
    int* bend_off_a = (int*)alloc((NG + 1) * sizeof(int));
    int* bend_cur   = (int*)alloc(NG * sizeof(int));
    int* bend_eids  = (int*)alloc(EBN * sizeof(int));
    int* bend_srcs  = (int*)alloc(EBN * sizeof(int));
    int* sec_off_a  = (int*)alloc((NN + 1) * sizeof(int));
    int* sec_cur    = (int*)alloc(NN * sizeof(int));
    int* sec_eids   = (int*)alloc(ESN * sizeof(int));
    int* sec_srcs   = (int*)alloc(ESN * sizeof(int));
    int* bend_cnt   = (int*)alloc(NG * sizeof(int));
    int* sec_cnt    = (int*)alloc(NN * sizeof(int));
    float* h_b      = (float*)alloc((size_t)BB * NG * CC * sizeof(float));
    float* h_s      = (float*)alloc((size_t)BB * NG * CC * sizeof(float));
    float* asb      = (float*)alloc((size_t)BB * NG * sizeof(float));
    float* adb      = (float*)alloc((size_t)BB * NG * sizeof(float));
    float* ass      = (float*)alloc((size_t)BB * NG * sizeof(float));
    float* ads      = (float*)alloc((size_t)BB * NG * sizeof(float));
    float* elog_b   = (float*)alloc((size_t)BB * EBN * sizeof(float));
    float* elog_s   = (float*)alloc((size_t)BB * ESN * sizeof(float));
    (void)ws_size; (void)in_sizes; (void)n_in; (void)out_size;

    prep_kernel<<<1, 64, 0, stream>>>(enc_W, enc_b, We_b, a_e_b, We_s, a_e_s, mix_w, P);
    zero_counts<<<(NG + 255) / 256, 256, 0, stream>>>(bend_cnt, sec_cnt);
    count_kernel<<<(EBN + 255) / 256, 256, 0, stream>>>(bend_ei, sec_ei, bend_cnt, sec_cnt);
    scan_kernel<<<2, 1024, 0, stream>>>(bend_cnt, bend_off_a, bend_cur, sec_cnt, sec_off_a, sec_cur);
    fill_kernel<<<(EBN + 255) / 256, 256, 0, stream>>>(bend_ei, sec_ei,
                                                       bend_cur, bend_eids, bend_srcs,
                                                       sec_cur, sec_eids, sec_srcs);
    {
        int waves = BB * NG;
        int blocks = (waves * 64 + 255) / 256;
        feat_kernel<<<blocks, 256, 0, stream>>>(x, Wb, a_src_b, a_dst_b, Ws, a_src_s, a_dst_s,
                                                h_b, h_s, asb, adb, ass, ads);
    }
    {
        int ntot = BB * EBN + BB * ESN;
        elog_kernel<<<(ntot + 255) / 256, 256, 0, stream>>>(bend_attr, sec_attr, P, elog_b, elog_s);
    }
    {
        int waves = BB * NG;
        int blocks = (waves * 64 + 255) / 256;
        gather_fused<<<blocks, 256, 0, stream>>>(bend_off_a, bend_srcs, bend_eids,
                                                 sec_off_a, sec_srcs, sec_eids,
                                                 h_b, h_s, asb, adb, ass, ads,
                                                 elog_b, elog_s, bias_b, bias_s, P, out);
    }
}

// Round 3
// 252.851 us; speedup vs baseline: 4.2517x; 1.2870x over previous
//
#include <hip/hip_runtime.h>
#include <math.h>

// Problem dims
#define BB 8
#define SS 32
#define NN 512
#define FIN 24
#define CC 56
#define EBN 262144
#define ESN 8192
#define EDD 4
#define NG (SS*NN)   // 16384 nodes per sample in bend graph
#define BCAP 128     // bucket capacity (avg deg 16, max ~35)
#define SCAP 128

// ---------------- small helpers ----------------
__device__ __forceinline__ float bf2f(unsigned short u) {
    union { unsigned int i; float f; } w; w.i = ((unsigned int)u) << 16; return w.f;
}
__device__ __forceinline__ unsigned short f2bf(float f) {
    union { float f; unsigned int i; } w; w.f = f;
    unsigned int r = (w.i + 0x7FFFu + ((w.i >> 16) & 1u)) >> 16;
    return (unsigned short)r;
}
__device__ __forceinline__ float wave_max(float v) {
    #pragma unroll
    for (int o = 32; o > 0; o >>= 1) v = fmaxf(v, __shfl_xor(v, o));
    return v;
}
__device__ __forceinline__ float wave_sum(float v) {
    #pragma unroll
    for (int o = 32; o > 0; o >>= 1) v += __shfl_xor(v, o);
    return v;
}

// ---------------- K0: prep params + zero bucket counts ----------------
// P layout: [0..3]=u_bend, [4]=c_bend, [5..8]=u_sec, [9]=c_sec, [10]=w0, [11]=w1
__global__ void k0_init(const float* enc_W, const float* enc_b,
                        const float* We_b, const float* a_e_b,
                        const float* We_s, const float* a_e_s,
                        const float* mix_w, float* P,
                        int* bcnt, int* scnt) {
    int i = blockIdx.x * blockDim.x + threadIdx.x;
    if (i < NG) bcnt[i] = 0;
    if (i < NN) scnt[i] = 0;
    if (i == 0) {
        float tb[EDD], ts[EDD];
        for (int j = 0; j < EDD; ++j) {
            float vb = 0.f, vs = 0.f;
            for (int c = 0; c < CC; ++c) {
                vb += We_b[j*CC + c] * a_e_b[c];
                vs += We_s[j*CC + c] * a_e_s[c];
            }
            tb[j] = vb; ts[j] = vs;
        }
        float cb = 0.f, cs = 0.f;
        for (int j = 0; j < EDD; ++j) { cb += enc_b[j]*tb[j]; cs += enc_b[j]*ts[j]; }
        for (int d = 0; d < EDD; ++d) {
            float ub = 0.f, us = 0.f;
            for (int j = 0; j < EDD; ++j) {
                ub += enc_W[d*EDD + j] * tb[j];
                us += enc_W[d*EDD + j] * ts[j];
            }
            P[d] = ub; P[5 + d] = us;
        }
        P[4] = cb; P[9] = cs;
        float m0 = mix_w[0], m1 = mix_w[1];
        float mm = fmaxf(m0, m1);
        float e0 = expf(m0 - mm), e1 = expf(m1 - mm);
        float inv = 1.f / (e0 + e1);
        P[10] = e0 * inv; P[11] = e1 * inv;
    }
}

// ---------------- K1: bucket fill + node features + edge logits (grid-partitioned)
#define FEAT_NB (BB*NG/4)              // 32768 blocks, 4 waves each
#define FILLB_NB ((EBN+255)/256)       // 1024
#define FILLS_NB ((ESN+255)/256)       // 32
#define ELOG_NB ((BB*(EBN+ESN)+255)/256) // 8448

__global__ __launch_bounds__(256) void k1_build(
        const float* __restrict__ x,
        const int* __restrict__ bend_ei, const int* __restrict__ sec_ei,
        const float* __restrict__ bend_attr, const float* __restrict__ sec_attr,
        const float* __restrict__ Wb, const float* __restrict__ a_src_b,
        const float* __restrict__ a_dst_b,
        const float* __restrict__ Ws, const float* __restrict__ a_src_s,
        const float* __restrict__ a_dst_s,
        const float* __restrict__ P,
        unsigned short* __restrict__ h_b, unsigned short* __restrict__ h_s,
        float* __restrict__ asb, float* __restrict__ adb,
        float* __restrict__ ass, float* __restrict__ ads,
        float* __restrict__ elog_b, float* __restrict__ elog_s,
        int* __restrict__ bcnt, int2* __restrict__ bbuck,
        int* __restrict__ scnt, int2* __restrict__ sbuck) {
    int blk = blockIdx.x;
    if (blk < FEAT_NB) {
        // ---- node features: h = x@W (bf16 store), alphas (fp32)
        int wave = (blk << 2) + (threadIdx.x >> 6);
        int lane = threadIdx.x & 63;
        size_t ng = (size_t)wave;
        const float4* x4 = (const float4*)(x + ng * FIN);
        float xv[FIN];
        #pragma unroll
        for (int q = 0; q < FIN/4; ++q) {
            float4 v = x4[q];
            xv[4*q+0] = v.x; xv[4*q+1] = v.y; xv[4*q+2] = v.z; xv[4*q+3] = v.w;
        }
        float hb = 0.f, hs = 0.f;
        if (lane < CC) {
            #pragma unroll
            for (int f = 0; f < FIN; ++f) {
                hb = fmaf(xv[f], Wb[f*CC + lane], hb);
                hs = fmaf(xv[f], Ws[f*CC + lane], hs);
            }
        }
        float vsb = (lane < CC) ? hb * a_src_b[lane] : 0.f;
        float vdb = (lane < CC) ? hb * a_dst_b[lane] : 0.f;
        float vss = (lane < CC) ? hs * a_src_s[lane] : 0.f;
        float vds = (lane < CC) ? hs * a_dst_s[lane] : 0.f;
        #pragma unroll
        for (int o = 32; o > 0; o >>= 1) {
            vsb += __shfl_down(vsb, o);
            vdb += __shfl_down(vdb, o);
            vss += __shfl_down(vss, o);
            vds += __shfl_down(vds, o);
        }
        if (lane == 0) { asb[ng] = vsb; adb[ng] = vdb; ass[ng] = vss; ads[ng] = vds; }
        if (lane < CC) { h_b[ng*CC + lane] = f2bf(hb); h_s[ng*CC + lane] = f2bf(hs); }
    } else if (blk < FEAT_NB + FILLB_NB) {
        // ---- bend bucket fill
        int i = (blk - FEAT_NB) * 256 + threadIdx.x;
        if (i < EBN) {
            int d = bend_ei[EBN + i];
            int p = atomicAdd(&bcnt[d], 1);
            if (p < BCAP) bbuck[(size_t)d * BCAP + p] = make_int2(bend_ei[i], i);
        }
    } else if (blk < FEAT_NB + FILLB_NB + FILLS_NB) {
        // ---- section bucket fill
        int i = (blk - FEAT_NB - FILLB_NB) * 256 + threadIdx.x;
        if (i < ESN) {
            int d = sec_ei[ESN + i];
            int p = atomicAdd(&scnt[d], 1);
            if (p < SCAP) sbuck[(size_t)d * SCAP + p] = make_int2(sec_ei[i], i);
        }
    } else {
        // ---- per-edge scalar logit terms
        int i = (blk - FEAT_NB - FILLB_NB - FILLS_NB) * 256 + threadIdx.x;
        const int nb = BB * EBN;
        if (i < nb) {
            float4 a = ((const float4*)bend_attr)[i];
            elog_b[i] = a.x*P[0] + a.y*P[1] + a.z*P[2] + a.w*P[3] + P[4];
        } else if (i < nb + BB * ESN) {
            int j = i - nb;
            float4 a = ((const float4*)sec_attr)[j];
            elog_s[j] = a.x*P[5] + a.y*P[6] + a.z*P[7] + a.w*P[8] + P[9];
        }
    }
}

// ---------------- GAT for one destination node, lane-parallel over edges ----------------
__device__ __forceinline__ float gat_bucket(const int2* __restrict__ buck, int deg,
                                            const float* __restrict__ asrc,
                                            const float* __restrict__ el,
                                            const unsigned short* __restrict__ h,
                                            float adg, int lane, int cl) {
    if (deg <= 0) return 0.f;
    float acc = 0.f, sum;
    if (deg <= 64) {
        bool v = lane < deg;
        int2 se = buck[v ? lane : 0];
        float lg = asrc[se.x] + adg + el[se.y];
        lg = lg >= 0.f ? lg : 0.2f * lg;
        float m = wave_max(v ? lg : -INFINITY);
        float p = v ? __expf(lg - m) : 0.f;   // invalid lanes carry p = 0
        sum = wave_sum(p);
        int degR = (deg + 7) & ~7;            // round up; extra lanes have p=0, s=buck[0].x
        for (int k = 0; k < degR; k += 8) {
            float pk[8]; int sk[8]; float hv[8];
            #pragma unroll
            for (int j = 0; j < 8; ++j) { pk[j] = __shfl(p, k + j); sk[j] = __shfl(se.x, k + j); }
            #pragma unroll
            for (int j = 0; j < 8; ++j) { hv[j] = bf2f(h[sk[j]*CC + cl]); }
            #pragma unroll
            for (int j = 0; j < 8; ++j) { acc = fmaf(pk[j], hv[j], acc); }
        }
    } else {
        // rare fallback (deg in (64, BCAP]): chunked two-pass
        float m = -INFINITY;
        for (int k0 = 0; k0 < deg; k0 += 64) {
            int k = k0 + lane;
            if (k < deg) {
                int2 se = buck[k];
                float lg = asrc[se.x] + adg + el[se.y];
                lg = lg >= 0.f ? lg : 0.2f * lg;
                m = fmaxf(m, lg);
            }
        }
        m = wave_max(m);
        sum = 0.f;
        for (int k0 = 0; k0 < deg; k0 += 64) {
            int k = k0 + lane;
            bool v = k < deg;
            int2 se = buck[v ? k : 0];
            float lg = asrc[se.x] + adg + el[se.y];
            lg = lg >= 0.f ? lg : 0.2f * lg;
            float p = v ? __expf(lg - m) : 0.f;
            sum += wave_sum(p);
            int valid = (deg - k0) < 64 ? (deg - k0) : 64;
            for (int k2 = 0; k2 < valid; ++k2) {
                float pk = __shfl(p, k2);
                int sk = __shfl(se.x, k2);
                acc = fmaf(pk, bf2f(h[sk*CC + cl]), acc);
            }
        }
    }
    return acc / (sum + 1e-16f);
}

// ---------------- K2: fused gather, XCD-pinned by batch (b = blockIdx & 7) ----------------
__global__ __launch_bounds__(256) void k2_gather(
        const int* __restrict__ bcnt, const int2* __restrict__ bbuck,
        const int* __restrict__ scnt, const int2* __restrict__ sbuck,
        const unsigned short* __restrict__ h_b, const unsigned short* __restrict__ h_s,
        const float* __restrict__ asb, const float* __restrict__ adb,
        const float* __restrict__ ass, const float* __restrict__ ads,
        const float* __restrict__ elog_b, const float* __restrict__ elog_s,
        const float* __restrict__ bias_b, const float* __restrict__ bias_s,
        const float* __restrict__ P, float* __restrict__ out) {
    int blk = blockIdx.x;
    int b = blk & 7;                               // XCD pin: round-robin blk->XCD
    int g = ((blk >> 3) << 2) + (threadIdx.x >> 6);
    int lane = threadIdx.x & 63;
    int cl = lane < CC ? lane : CC - 1;

    int degb = bcnt[g]; degb = degb < BCAP ? degb : BCAP;
    float vb = gat_bucket(bbuck + (size_t)g * BCAP, degb,
                          asb + (size_t)b * NG, elog_b + (size_t)b * EBN,
                          h_b + (size_t)b * NG * CC,
                          adb[(size_t)b * NG + g], lane, cl);

    int sct = g >> 9;            // NN = 2^9
    int n = g & (NN - 1);
    size_t basebg = (size_t)b * NG + (size_t)sct * NN;
    int degs = scnt[n]; degs = degs < SCAP ? degs : SCAP;
    float vs = gat_bucket(sbuck + (size_t)n * SCAP, degs,
                          ass + basebg, elog_s + (size_t)b * ESN,
                          h_s + basebg * CC,
                          ads[basebg + n], lane, cl);

    if (lane < CC) {
        float ob = vb + bias_b[lane];
        ob = ob >= 0.f ? ob : 0.01f * ob;
        float os = vs + bias_s[lane];
        out[((size_t)b * NG + g) * CC + lane] = P[10] * ob + P[11] * os;
    }
}

extern "C" void kernel_launch(void* const* d_in, const int* in_sizes, int n_in,
                              void* d_out, int out_size, void* d_ws, size_t ws_size,
                              hipStream_t stream) {
    const float* x          = (const float*)d_in[0];
    const int*   bend_ei    = (const int*)d_in[1];
    const int*   sec_ei     = (const int*)d_in[2];
    const float* bend_attr  = (const float*)d_in[3];
    const float* sec_attr   = (const float*)d_in[4];
    const float* enc_W      = (const float*)d_in[5];
    const float* enc_b      = (const float*)d_in[6];
    const float* Wb         = (const float*)d_in[7];
    const float* a_src_b    = (const float*)d_in[8];
    const float* a_dst_b    = (const float*)d_in[9];
    const float* We_b       = (const float*)d_in[10];
    const float* a_e_b      = (const float*)d_in[11];
    const float* bias_b     = (const float*)d_in[12];
    const float* Ws         = (const float*)d_in[13];
    const float* a_src_s    = (const float*)d_in[14];
    const float* a_dst_s    = (const float*)d_in[15];
    const float* We_s       = (const float*)d_in[16];
    const float* a_e_s      = (const float*)d_in[17];
    const float* bias_s     = (const float*)d_in[18];
    const float* mix_w      = (const float*)d_in[19];
    float* out = (float*)d_out;

    char* base = (char*)d_ws;
    size_t off = 0;
    auto alloc = [&](size_t bytes) -> char* {
        off = (off + 255) & ~(size_t)255;
        char* p = base + off;
        off += bytes;
        return p;
    };
    float* P       = (float*)alloc(64 * sizeof(float));
    int* bcnt      = (int*)alloc(NG * sizeof(int));
    int* scnt      = (int*)alloc(NN * sizeof(int));
    int2* bbuck    = (int2*)alloc((size_t)NG * BCAP * sizeof(int2));
    int2* sbuck    = (int2*)alloc((size_t)NN * SCAP * sizeof(int2));
    unsigned short* h_b = (unsigned short*)alloc((size_t)BB * NG * CC * sizeof(unsigned short));
    unsigned short* h_s = (unsigned short*)alloc((size_t)BB * NG * CC * sizeof(unsigned short));
    float* asb     = (float*)alloc((size_t)BB * NG * sizeof(float));
    float* adb     = (float*)alloc((size_t)BB * NG * sizeof(float));
    float* ass     = (float*)alloc((size_t)BB * NG * sizeof(float));
    float* ads     = (float*)alloc((size_t)BB * NG * sizeof(float));
    float* elog_b  = (float*)alloc((size_t)BB * EBN * sizeof(float));
    float* elog_s  = (float*)alloc((size_t)BB * ESN * sizeof(float));
    (void)ws_size; (void)in_sizes; (void)n_in; (void)out_size;

    k0_init<<<(NG + 255) / 256, 256, 0, stream>>>(enc_W, enc_b, We_b, a_e_b, We_s, a_e_s,
                                                  mix_w, P, bcnt, scnt);

    int k1_blocks = FEAT_NB + FILLB_NB + FILLS_NB + ELOG_NB;
    k1_build<<<k1_blocks, 256, 0, stream>>>(x, bend_ei, sec_ei, bend_attr, sec_attr,
                                            Wb, a_src_b, a_dst_b, Ws, a_src_s, a_dst_s,
                                            P, h_b, h_s, asb, adb, ass, ads,
                                            elog_b, elog_s, bcnt, bbuck, scnt, sbuck);

    int k2_blocks = 8 * (NG / 4);   // b = blk & 7, 4 nodes per block
    k2_gather<<<k2_blocks, 256, 0, stream>>>(bcnt, bbuck, scnt, sbuck, h_b, h_s,
                                             asb, adb, ass, ads, elog_b, elog_s,
                                             bias_b, bias_s, P, out);
}